// Round 2
// baseline (2618.225 us; speedup 1.0000x reference)
//
#include <hip/hip_runtime.h>

constexpr int G  = 8;
constexpr int NN = 50000;
constexpr int EE = 800000;
constexpr int F  = 128;

typedef float float4_t __attribute__((ext_vector_type(4)));

// ---------------- graph structure build ----------------
// edge_index is int32 on device (JAX default x64-disabled downcasts int64->int32;
// harness contract: integer inputs -> const int*). Layout [G, 2, E].

__global__ __launch_bounds__(256) void deg_kernel(const int* __restrict__ edges,
                                                  int* __restrict__ deg, int gbase) {
  int gw = blockIdx.y;
  size_t ebase = ((size_t)(gbase + gw) * 2 + 1) * EE;   // dst half
  int e = blockIdx.x * 256 + threadIdx.x;               // grid.x * 256 == EE exactly
  int dst = edges[ebase + e];
  atomicAdd(&deg[gw * NN + dst], 1);
}

// one block per (chunk-local) graph: exclusive scan of deg -> row_off, dinv, reset deg->cursor
__global__ __launch_bounds__(1024) void scan_kernel(int* __restrict__ deg, int* __restrict__ row_off,
                                                    float* __restrict__ dinv) {
  int gw  = blockIdx.x;
  int tid = threadIdx.x;
  int lane = tid & 63, wid = tid >> 6;
  __shared__ int wsum[16];
  __shared__ int carry_s;
  if (tid == 0) carry_s = 0;
  __syncthreads();
  int*   dg = deg + gw * NN;
  int*   ro = row_off + gw * (NN + 1);
  float* dv = dinv + gw * NN;
  for (int base = 0; base < NN; base += 1024) {
    int i = base + tid;
    int v = 0;
    if (i < NN) {
      v = dg[i];
      dv[i] = rsqrtf((float)v + 1.0f);
      dg[i] = 0;  // becomes cursor for fill_kernel
    }
    int incl = v;
    #pragma unroll
    for (int off = 1; off < 64; off <<= 1) {
      int t = __shfl_up(incl, off);
      if (lane >= off) incl += t;
    }
    if (lane == 63) wsum[wid] = incl;
    __syncthreads();
    if (tid == 0) {
      int s = 0;
      #pragma unroll
      for (int w = 0; w < 16; ++w) { int t = wsum[w]; wsum[w] = s; s += t; }
    }
    __syncthreads();
    int excl = carry_s + wsum[wid] + (incl - v);
    if (i < NN) ro[i] = excl;
    __syncthreads();
    if (tid == 1023) carry_s = excl + v;   // old carry + chunk total
    __syncthreads();
  }
  if (tid == 0) ro[NN] = carry_s;          // == EE
}

__global__ __launch_bounds__(256) void fill_kernel(const int* __restrict__ edges,
                                                   int* __restrict__ cursor, const int* __restrict__ row_off,
                                                   int* __restrict__ csr, int gbase) {
  int gw = blockIdx.y;
  size_t ebase = (size_t)(gbase + gw) * 2 * EE;
  int e = blockIdx.x * 256 + threadIdx.x;
  int src = edges[ebase + e];
  int dst = edges[ebase + EE + e];
  int slot = atomicAdd(&cursor[gw * NN + dst], 1);
  csr[(size_t)gw * EE + row_off[gw * (NN + 1) + dst] + slot] = src;
}

// ---------------- per-layer compute ----------------

// h1 = h @ W   (f32 vector GEMM, 128-row x 128-col tile per block, 512 threads)
__global__ __launch_bounds__(512) void gemm_kernel(const float* __restrict__ h, const float* __restrict__ W,
                                                   float* __restrict__ h1, int gbase) {
  __shared__ float Al[128 * F];   // 64 KB
  __shared__ float Wl[F * F];     // 64 KB
  int gw = blockIdx.y;
  int g  = gbase + gw;
  int row0 = blockIdx.x * 128;
  int tid = threadIdx.x;
  const float* hg  = h  + (size_t)g  * NN * F;   // inputs: true graph index
  float*       h1g = h1 + (size_t)gw * NN * F;   // ws: chunk-local index
  int cseg = tid & 31, rb = tid >> 5;            // cseg: 4-col group, rb in [0,16)
  #pragma unroll
  for (int rr = 0; rr < 128; rr += 16) {
    int r = rr + rb;
    int grow = row0 + r;
    float4_t v = {0.f, 0.f, 0.f, 0.f};
    if (grow < NN) v = *(const float4_t*)(hg + (size_t)grow * F + cseg * 4);
    *(float4_t*)(Al + r * F + cseg * 4) = v;
    *(float4_t*)(Wl + r * F + cseg * 4) = *(const float4_t*)(W + r * F + cseg * 4);
  }
  __syncthreads();
  float4_t acc[8];
  #pragma unroll
  for (int i = 0; i < 8; ++i) acc[i] = (float4_t){0.f, 0.f, 0.f, 0.f};
  #pragma unroll 4
  for (int k = 0; k < F; ++k) {
    float4_t w = *(const float4_t*)(Wl + k * F + cseg * 4);
    #pragma unroll
    for (int i = 0; i < 8; ++i) {
      float a = Al[(rb + 16 * i) * F + k];   // broadcast within half-wave
      acc[i][0] = fmaf(a, w[0], acc[i][0]);
      acc[i][1] = fmaf(a, w[1], acc[i][1]);
      acc[i][2] = fmaf(a, w[2], acc[i][2]);
      acc[i][3] = fmaf(a, w[3], acc[i][3]);
    }
  }
  #pragma unroll
  for (int i = 0; i < 8; ++i) {
    int grow = row0 + rb + 16 * i;
    if (grow < NN) *(float4_t*)(h1g + (size_t)grow * F + cseg * 4) = acc[i];
  }
}

// out[n] = relu(dinv[n]*(h1[n]*dinv[n] + sum_src h1[src]*dinv[src]) + b)
// 32 lanes per node (float4/lane), 8 nodes per 256-thread block
__global__ __launch_bounds__(256) void agg_kernel(const float* __restrict__ h1, const int* __restrict__ csr,
                                                  const int* __restrict__ row_off, const float* __restrict__ dinv,
                                                  const float* __restrict__ bias, float* __restrict__ out,
                                                  int gbase) {
  int gw = blockIdx.y;
  int g  = gbase + gw;
  int grp = threadIdx.x >> 5, lane = threadIdx.x & 31;
  int node = blockIdx.x * 8 + grp;
  if (node >= NN) return;
  const float* hg = h1 + (size_t)gw * NN * F;
  const float* dv = dinv + (size_t)gw * NN;
  const int*   cs = csr + (size_t)gw * EE;
  int e0 = row_off[gw * (NN + 1) + node];
  int e1 = row_off[gw * (NN + 1) + node + 1];
  float di = dv[node];
  float4_t acc = *(const float4_t*)(hg + (size_t)node * F + lane * 4) * di;  // self-loop term
  int e = e0;
  for (; e + 1 < e1; e += 2) {
    int s0 = cs[e], s1 = cs[e + 1];
    float d0 = dv[s0], d1 = dv[s1];
    float4_t v0 = *(const float4_t*)(hg + (size_t)s0 * F + lane * 4);
    float4_t v1 = *(const float4_t*)(hg + (size_t)s1 * F + lane * 4);
    acc += v0 * d0 + v1 * d1;
  }
  if (e < e1) {
    int s = cs[e];
    acc += *(const float4_t*)(hg + (size_t)s * F + lane * 4) * dv[s];
  }
  float4_t bb = *(const float4_t*)(bias + lane * 4);
  float4_t o;
  #pragma unroll
  for (int j = 0; j < 4; ++j) o[j] = fmaxf(fmaf(acc[j], di, bb[j]), 0.f);
  *(float4_t*)(out + (size_t)g * NN * F + (size_t)node * F + lane * 4) = o;
}

// ---------------- host launch ----------------

extern "C" void kernel_launch(void* const* d_in, const int* in_sizes, int n_in,
                              void* d_out, int out_size, void* d_ws, size_t ws_size,
                              hipStream_t stream) {
  const float* x     = (const float*)d_in[0];
  const int*   edges = (const int*)d_in[1];
  const float* Ws[3] = {(const float*)d_in[2], (const float*)d_in[4], (const float*)d_in[6]};
  const float* bs[3] = {(const float*)d_in[3], (const float*)d_in[5], (const float*)d_in[7]};
  float* out = (float*)d_out;

  // per-(chunked)graph workspace: h1 first (16B-aligned vector loads), then csr/deg/dinv/row_off
  size_t sz_h1  = (size_t)NN * F * 4;     // 25,600,000
  size_t sz_csr = (size_t)EE * 4;         //  3,200,000
  size_t sz_deg = (size_t)NN * 4;         //    200,000
  size_t sz_dv  = (size_t)NN * 4;
  size_t sz_ro  = (size_t)(NN + 1) * 4;
  size_t per_g  = sz_h1 + sz_csr + sz_deg + sz_dv + sz_ro;  // ~29.4 MB

  int C = (int)(ws_size / per_g);
  if (C < 1) C = 1;
  if (C > G) C = G;

  char* p = (char*)d_ws;
  float* h1      = (float*)p;  p += sz_h1  * C;
  int*   csr     = (int*)p;    p += sz_csr * C;
  int*   deg     = (int*)p;    p += sz_deg * C;   // doubles as cursor
  float* dinv    = (float*)p;  p += sz_dv  * C;
  int*   row_off = (int*)p;

  for (int g0 = 0; g0 < G; g0 += C) {
    int Cg = G - g0 < C ? G - g0 : C;
    hipMemsetAsync(deg, 0, (size_t)Cg * NN * 4, stream);
    deg_kernel <<<dim3(EE / 256, Cg), 256, 0, stream>>>(edges, deg, g0);
    scan_kernel<<<Cg, 1024, 0, stream>>>(deg, row_off, dinv);
    fill_kernel<<<dim3(EE / 256, Cg), 256, 0, stream>>>(edges, deg, row_off, csr, g0);
    for (int l = 0; l < 3; ++l) {
      const float* hin = (l == 0) ? x : out;   // activations ping-pong ws_h1 <-> d_out
      gemm_kernel<<<dim3((NN + 127) / 128, Cg), 512, 0, stream>>>(hin, Ws[l], h1, g0);
      agg_kernel <<<dim3((NN + 7) / 8, Cg), 256, 0, stream>>>(h1, csr, row_off, dinv, bs[l], out, g0);
    }
  }
}